// Round 1
// baseline (145.273 us; speedup 1.0000x reference)
//
#include <hip/hip_runtime.h>
#include <hip/hip_bf16.h>

// RGCN fused: per-relation aggregate (gather, fp32 acc) -> MFMA GEMM (K=8*64=512).
// Round 6 restructure:
//  - Gather is wave-per-node: lane = channel, relation tag is wave-uniform ->
//    readfirstlane + scalar switch -> 1 VALU add per edge (was 32 predicated
//    FMAs in the quad scheme). Loads stay one coalesced 256-B request/edge,
//    12 in flight per node from a single basic block (scalar saddr form).
//  - NPB 64 -> 32: LDS 71 KB -> ~36 KB -> 4 blocks/CU = 32 waves/CU (was 16).
//    __launch_bounds__(512,8) caps VGPR at 64 to guarantee it.
// W stays pre-packed as bf16 B-fragments in d_ws (L2-hot), pack_w unchanged.

#define THREADS 512
#define NPB 32            // nodes per block
#define KDIM 512          // NUM_REL * IN_CH
#define LDA 520           // padded bf16 row stride (1040 B)
#define MAXE 512          // LDS edge-meta capacity (deg 12 -> 384 used)
#define WFRAG (4 * 16 * 64 * 8)   // 32768 bf16 B-fragment elements

typedef __attribute__((ext_vector_type(8))) short bf16x8;
typedef __attribute__((ext_vector_type(4))) float f32x4;

extern __shared__ __align__(16) char smem[];

__device__ __forceinline__ unsigned short f2bf(float f) {
  __hip_bfloat16 h = __float2bfloat16(f);
  return *reinterpret_cast<unsigned short*>(&h);
}

// ---- pack W (fp32 or bf16, [512][64]) -> bf16 B-fragment order in ws ----
// frag element i = ((nt*16+kt)*64 + lane)*8 + j  holds  W[kt*32+(lane>>4)*8+j][nt*16+(lane&15)]
__global__ __launch_bounds__(256) void pack_w(const void* __restrict__ wv,
                                              unsigned short* __restrict__ wsB) {
  const int lane = threadIdx.x & 63;
  const unsigned word = ((const unsigned*)wv)[lane];
  const int exf = (int)((word >> 7) & 0xFFu);
  const bool w_bf16 = __popcll(__ballot(exf >= 96 && exf < 160)) >= 48;
  for (int i = blockIdx.x * 256 + threadIdx.x; i < WFRAG; i += gridDim.x * 256) {
    const int j  = i & 7;
    const int l  = (i >> 3) & 63;
    const int kt = (i >> 9) & 15;
    const int nt = i >> 13;
    const int k  = kt * 32 + (l >> 4) * 8 + j;
    const int n  = nt * 16 + (l & 15);
    float v;
    if (w_bf16) v = __bfloat162float(((const __hip_bfloat16*)wv)[k * 64 + n]);
    else        v = ((const float*)wv)[k * 64 + n];
    wsB[i] = f2bf(v);
  }
}

#define ACC_SW(accrow, r, vv)                                        \
  switch (r) {                                                       \
    case 0: accrow[0] += (vv); break; case 1: accrow[1] += (vv); break; \
    case 2: accrow[2] += (vv); break; case 3: accrow[3] += (vv); break; \
    case 4: accrow[4] += (vv); break; case 5: accrow[5] += (vv); break; \
    case 6: accrow[6] += (vv); break; default: accrow[7] += (vv); break; }

__global__ __launch_bounds__(THREADS, 8)
void rgcn_fused(const void* __restrict__ xv,
                const void* __restrict__ wv,
                const int* __restrict__ p32,
                const int* __restrict__ i32,
                const int* __restrict__ t32,
                const unsigned short* __restrict__ wsB,  // null -> W staged in LDS
                float* __restrict__ out,
                int num_nodes) {
  __hip_bfloat16* aggS = (__hip_bfloat16*)smem;                 // [NPB][LDA]
  __hip_bfloat16* wtS  = aggS + NPB * LDA;                      // only if !wsB
  char* tail = smem + (size_t)NPB * LDA * 2 + (wsB ? 0 : (size_t)64 * LDA * 2);
  float*    invS  = (float*)tail;                               // [NPB]
  int*      ptrS  = (int*)(tail + 256);                         // [NPB+1]
  unsigned* eMeta = (unsigned*)(tail + 256 + 144);              // [MAXE]

  const int tid   = threadIdx.x;
  const int lane  = tid & 63;
  const int wvid  = tid >> 6;
  const int node0 = blockIdx.x * NPB;

  // runtime dtype / index-width detection (block-uniform)
  const unsigned xword = ((const unsigned*)xv)[lane];
  const int exf = (int)((xword >> 7) & 0xFFu);
  const bool x_bf16 = __popcll(__ballot(exf >= 96 && exf < 160)) >= 48;
  const bool idx64 = (p32[1] == 0);

  auto ldptr = [&](int n) -> int { return idx64 ? p32[2 * n] : p32[n]; };

  const int ntop   = min(node0 + NPB, num_nodes);
  const int e_lo   = ldptr(node0);
  const int ecount = ldptr(ntop) - e_lo;
  const bool staged = (ecount > 0 && ecount <= MAXE);

  for (int i = tid; i <= NPB; i += THREADS)
    ptrS[i] = ldptr(min(node0 + i, num_nodes));

  if (staged) {
    for (int e = tid; e < ecount; e += THREADS) {
      const int ge = e_lo + e;
      const unsigned s = (unsigned)(idx64 ? i32[2 * ge] : i32[ge]);
      const unsigned r = (unsigned)(idx64 ? t32[2 * ge] : t32[ge]);
      eMeta[e] = s | (r << 24);
    }
  }

  if (!wsB) {  // fallback: stage W^T in LDS (rare; only if ws too small)
    if (x_bf16) {
      const __hip_bfloat16* wb = (const __hip_bfloat16*)wv;
      for (int i = tid; i < KDIM * 64; i += THREADS)
        wtS[(i & 63) * LDA + (i >> 6)] = wb[i];
    } else {
      const float* wf = (const float*)wv;
      for (int i = tid; i < KDIM * 64; i += THREADS)
        wtS[(i & 63) * LDA + (i >> 6)] = __float2bfloat16(wf[i]);
    }
  }

  __syncthreads();

  // inverse degree (reads ptrS; consumed after next barrier)
  for (int i = tid; i < NPB; i += THREADS) {
    const int d = ptrS[i + 1] - ptrS[i];
    invS[i] = (d > 0 && node0 + i < num_nodes) ? 1.0f / (float)d : 0.0f;
  }

  // ---- gather: wave wvid owns nodes wvid*4 .. wvid*4+3; lane = channel ----
  // Relation tag is wave-uniform per edge -> scalar switch, 1 add/edge/lane.
  auto gather = [&](auto lc) {
    for (int t = 0; t < 4; ++t) {
      const int nl  = wvid * 4 + t;
      const int pe0 = __builtin_amdgcn_readfirstlane(ptrS[nl]);
      const int pe1 = __builtin_amdgcn_readfirstlane(ptrS[nl + 1]);
      const int e0  = pe0 - e_lo;
      const int dg  = pe1 - pe0;
      const bool inb = (node0 + nl < num_nodes);
      if (staged && inb && dg == 12) {
        // phase 1: edge meta, broadcast LDS reads -> scalarized
        int m[12];
#pragma unroll
        for (int j = 0; j < 12; ++j)
          m[j] = __builtin_amdgcn_readfirstlane((int)eMeta[e0 + j]);
        // phase 2: 12 independent coalesced row loads (saddr + lane offset),
        // all in flight from one basic block
        float v[12];
#pragma unroll
        for (int j = 0; j < 12; ++j)
          v[j] = lc((int)((unsigned)m[j] & 0x00FFFFFFu));
        // phase 3: wave-uniform relation dispatch -> 1 VALU add per edge
        float acc[8] = {0.f, 0.f, 0.f, 0.f, 0.f, 0.f, 0.f, 0.f};
#pragma unroll
        for (int j = 0; j < 12; ++j) {
          const int r = (int)((unsigned)m[j] >> 24);
          ACC_SW(acc, r, v[j])
        }
#pragma unroll
        for (int r = 0; r < 8; ++r)
          aggS[nl * LDA + r * 64 + lane] = __float2bfloat16(acc[r]);
      } else {
        // generic: any degree; OOB rows -> zeros
        float a[8] = {0.f, 0.f, 0.f, 0.f, 0.f, 0.f, 0.f, 0.f};
        if (inb) {
          const int ee0 = pe0 - e_lo, ee1 = pe1 - e_lo;
          for (int e = ee0; e < ee1; ++e) {
            unsigned mm;
            if (staged) mm = eMeta[e];
            else {
              const int ge = e_lo + e;
              mm = (unsigned)(idx64 ? i32[2 * ge] : i32[ge]) |
                   ((unsigned)(idx64 ? t32[2 * ge] : t32[ge]) << 24);
            }
            const float vv = lc((int)(mm & 0x00FFFFFFu));
            const int r = __builtin_amdgcn_readfirstlane((int)(mm >> 24));
            ACC_SW(a, r, vv)
          }
        }
#pragma unroll
        for (int r = 0; r < 8; ++r)
          aggS[nl * LDA + r * 64 + lane] = __float2bfloat16(a[r]);
      }
    }
  };

  if (x_bf16) {
    auto lc = [&](int s) -> float {
      const unsigned short u = ((const unsigned short*)xv)[((size_t)s << 6) + lane];
      return __uint_as_float((unsigned)u << 16);
    };
    gather(lc);
  } else {
    auto lc = [&](int s) -> float {
      return ((const float*)xv)[((size_t)s << 6) + lane];
    };
    gather(lc);
  }

  __syncthreads();

  // ---- MFMA: out_tile[32x64] = agg[32x512] @ Wcat[512x64] ----
  // 8 waves: mt = wvid>>2 (0..1 row-tiles), nt = wvid&3 (0..3 col-tiles)
  const int mt = wvid >> 2;
  const int nt = wvid & 3;
  const int mi = lane & 15;
  const int q4 = lane >> 4;
  const __hip_bfloat16* ap = aggS + (mt * 16 + mi) * LDA + q4 * 8;
  f32x4 c0 = {0.f, 0.f, 0.f, 0.f};
  if (wsB) {
    const bf16x8* B = (const bf16x8*)wsB;
#pragma unroll
    for (int kt = 0; kt < KDIM / 32; ++kt) {
      const bf16x8 a = *(const bf16x8*)(ap + kt * 32);
      const bf16x8 b = B[(nt * 16 + kt) * 64 + lane];
      c0 = __builtin_amdgcn_mfma_f32_16x16x32_bf16(a, b, c0, 0, 0, 0);
    }
  } else {
    const __hip_bfloat16* bp = wtS + (nt * 16 + mi) * LDA + q4 * 8;
#pragma unroll
    for (int kt = 0; kt < KDIM / 32; ++kt) {
      const bf16x8 a = *(const bf16x8*)(ap + kt * 32);
      const bf16x8 b = *(const bf16x8*)(bp + kt * 32);
      c0 = __builtin_amdgcn_mfma_f32_16x16x32_bf16(a, b, c0, 0, 0, 0);
    }
  }

  // D layout: col = lane&15, row = q4*4 + reg -> fp32 stores
#pragma unroll
  for (int i = 0; i < 4; ++i) {
    const int row  = q4 * 4 + i;
    const int nl   = mt * 16 + row;
    const int node = node0 + nl;
    if (node < num_nodes) {
      out[(size_t)node * 64 + nt * 16 + mi] = c0[i] * invS[nl];
    }
  }
}

extern "C" void kernel_launch(void* const* d_in, const int* in_sizes, int n_in,
                              void* d_out, int out_size, void* d_ws, size_t ws_size,
                              hipStream_t stream) {
  const void* x   = d_in[0];
  const void* w   = d_in[1];
  const int*  ptr = (const int*)d_in[2];
  const int*  idx = (const int*)d_in[3];
  const int*  et  = (const int*)d_in[4];
  float*      out = (float*)d_out;

  const int num_nodes = in_sizes[0] / 64;   // x is [N, 64]

  const bool useWs = (d_ws != nullptr) &&
                     (ws_size >= (size_t)WFRAG * sizeof(unsigned short));
  unsigned short* wsB = useWs ? (unsigned short*)d_ws : nullptr;
  if (useWs) pack_w<<<32, 256, 0, stream>>>(w, wsB);

  const size_t lds_bytes = (size_t)NPB * LDA * 2 +
                           (useWs ? 0 : (size_t)64 * LDA * 2) +
                           256 + 144 + (size_t)MAXE * 4;

  hipFuncSetAttribute((const void*)rgcn_fused,
                      hipFuncAttributeMaxDynamicSharedMemorySize,
                      (int)lds_bytes);

  const int nblocks = (num_nodes + NPB - 1) / NPB;
  rgcn_fused<<<nblocks, THREADS, lds_bytes, stream>>>(x, w, ptr, idx, et, wsB,
                                                      out, num_nodes);
}

// Round 2
// 134.288 us; speedup vs baseline: 1.0818x; 1.0818x over previous
//
#include <hip/hip_runtime.h>
#include <hip/hip_bf16.h>

// RGCN fused: per-relation aggregate (gather, fp32 acc) -> MFMA GEMM (K=8*64=512).
// Round 7: quad-gather restored (1KB dwordx4 loads won empirically over
// wave-per-node dword loads, r6 regression), combined with NPB=32 occupancy:
//  - LDS ~35.7 KB -> 3-4 blocks/CU (24-32 waves) vs 2 blocks at NPB=64.
//  - Relation dispatch via f32x4 packed math -> v_pk_fma_f32 (2 ops / 4 ch).
//  - Edges in 2 batches of 6 to bound VGPR (6 float4 in flight + 8 f32x4 acc).
// W stays pre-packed as bf16 B-fragments in d_ws (L2-hot), pack_w unchanged.

#define THREADS 512
#define NPB 32            // nodes per block
#define KDIM 512          // NUM_REL * IN_CH
#define LDA 520           // padded bf16 row stride (1040 B)
#define MAXE 512          // LDS edge-meta capacity (deg 12 -> 384 used)
#define WFRAG (4 * 16 * 64 * 8)   // 32768 bf16 B-fragment elements

typedef __attribute__((ext_vector_type(8))) short bf16x8;
typedef __attribute__((ext_vector_type(4))) float f32x4;

extern __shared__ __align__(16) char smem[];

__device__ __forceinline__ unsigned short f2bf(float f) {
  __hip_bfloat16 h = __float2bfloat16(f);
  return *reinterpret_cast<unsigned short*>(&h);
}

// ---- pack W (fp32 or bf16, [512][64]) -> bf16 B-fragment order in ws ----
// frag element i = ((nt*16+kt)*64 + lane)*8 + j  holds  W[kt*32+(lane>>4)*8+j][nt*16+(lane&15)]
__global__ __launch_bounds__(256) void pack_w(const void* __restrict__ wv,
                                              unsigned short* __restrict__ wsB) {
  const int lane = threadIdx.x & 63;
  const unsigned word = ((const unsigned*)wv)[lane];
  const int exf = (int)((word >> 7) & 0xFFu);
  const bool w_bf16 = __popcll(__ballot(exf >= 96 && exf < 160)) >= 48;
  for (int i = blockIdx.x * 256 + threadIdx.x; i < WFRAG; i += gridDim.x * 256) {
    const int j  = i & 7;
    const int l  = (i >> 3) & 63;
    const int kt = (i >> 9) & 15;
    const int nt = i >> 13;
    const int k  = kt * 32 + (l >> 4) * 8 + j;
    const int n  = nt * 16 + (l & 15);
    float v;
    if (w_bf16) v = __bfloat162float(((const __hip_bfloat16*)wv)[k * 64 + n]);
    else        v = ((const float*)wv)[k * 64 + n];
    wsB[i] = f2bf(v);
  }
}

#define ACC_SW(accrow, r, vv)                                        \
  switch (r) {                                                       \
    case 0: accrow[0] += (vv); break; case 1: accrow[1] += (vv); break; \
    case 2: accrow[2] += (vv); break; case 3: accrow[3] += (vv); break; \
    case 4: accrow[4] += (vv); break; case 5: accrow[5] += (vv); break; \
    case 6: accrow[6] += (vv); break; default: accrow[7] += (vv); break; }

__global__ __launch_bounds__(THREADS, 6)
void rgcn_fused(const void* __restrict__ xv,
                const void* __restrict__ wv,
                const int* __restrict__ p32,
                const int* __restrict__ i32,
                const int* __restrict__ t32,
                const unsigned short* __restrict__ wsB,  // null -> W staged in LDS
                float* __restrict__ out,
                int num_nodes) {
  __hip_bfloat16* aggS = (__hip_bfloat16*)smem;                 // [NPB][LDA]
  __hip_bfloat16* wtS  = aggS + NPB * LDA;                      // only if !wsB
  char* tail = smem + (size_t)NPB * LDA * 2 + (wsB ? 0 : (size_t)64 * LDA * 2);
  float*    invS  = (float*)tail;                               // [NPB]
  int*      ptrS  = (int*)(tail + 256);                         // [NPB+1]
  unsigned* eMeta = (unsigned*)(tail + 256 + 144);              // [MAXE]

  const int tid   = threadIdx.x;
  const int lane  = tid & 63;
  const int wvid  = tid >> 6;
  const int node0 = blockIdx.x * NPB;

  // runtime dtype / index-width detection (block-uniform)
  const unsigned xword = ((const unsigned*)xv)[lane];
  const int exf = (int)((xword >> 7) & 0xFFu);
  const bool x_bf16 = __popcll(__ballot(exf >= 96 && exf < 160)) >= 48;
  const bool idx64 = (p32[1] == 0);

  auto ldptr = [&](int n) -> int { return idx64 ? p32[2 * n] : p32[n]; };

  const int ntop   = min(node0 + NPB, num_nodes);
  const int e_lo   = ldptr(node0);
  const int ecount = ldptr(ntop) - e_lo;
  const bool staged = (ecount > 0 && ecount <= MAXE);

  for (int i = tid; i <= NPB; i += THREADS)
    ptrS[i] = ldptr(min(node0 + i, num_nodes));

  if (staged) {
    for (int e = tid; e < ecount; e += THREADS) {
      const int ge = e_lo + e;
      const unsigned s = (unsigned)(idx64 ? i32[2 * ge] : i32[ge]);
      const unsigned r = (unsigned)(idx64 ? t32[2 * ge] : t32[ge]);
      eMeta[e] = s | (r << 24);
    }
  }

  if (!wsB) {  // fallback: stage W^T in LDS (rare; only if ws too small)
    if (x_bf16) {
      const __hip_bfloat16* wb = (const __hip_bfloat16*)wv;
      for (int i = tid; i < KDIM * 64; i += THREADS)
        wtS[(i & 63) * LDA + (i >> 6)] = wb[i];
    } else {
      const float* wf = (const float*)wv;
      for (int i = tid; i < KDIM * 64; i += THREADS)
        wtS[(i & 63) * LDA + (i >> 6)] = __float2bfloat16(wf[i]);
    }
  }

  __syncthreads();

  // inverse degree (reads ptrS; consumed after next barrier)
  for (int i = tid; i < NPB; i += THREADS) {
    const int d = ptrS[i + 1] - ptrS[i];
    invS[i] = (d > 0 && node0 + i < num_nodes) ? 1.0f / (float)d : 0.0f;
  }

  const int c16 = lane & 15;
  const int qd  = lane >> 4;

  // ---- gather: wave owns 4 nodes (one group); quad qd owns node nlb+qd ----
  auto gather = [&](auto xp, auto loadrow) {
    const int nlb = wvid * 4;
    const int eq0 = ptrS[nlb + qd] - e_lo;          // quad-uniform per lane
    const int dq  = ptrS[nlb + qd + 1] - e_lo - eq0;
    const bool okfast = staged && (node0 + nlb + 3 < num_nodes) &&
                        (__ballot(dq == 12) == ~0ull);
    if (okfast) {
      f32x4 acc[8];
#pragma unroll
      for (int r = 0; r < 8; ++r) acc[r] = (f32x4){0.f, 0.f, 0.f, 0.f};
      // 2 batches of 6 edges: 6 dwordx4 (1 KB each) in flight, then packed
      // predicated accumulate (v_pk_fma_f32: 2 ops per 4 channels).
#pragma unroll
      for (int h = 0; h < 2; ++h) {
        unsigned mB[6];
#pragma unroll
        for (int j = 0; j < 6; ++j) mB[j] = eMeta[eq0 + h * 6 + j];
        f32x4 v[6];
#pragma unroll
        for (int j = 0; j < 6; ++j)
          v[j] = loadrow((int)(mB[j] & 0x00FFFFFFu), c16);
#pragma unroll
        for (int j = 0; j < 6; ++j) {
          const unsigned rj = mB[j] >> 24;
#pragma unroll
          for (int r = 0; r < 8; ++r) {
            const float mk = (rj == (unsigned)r) ? 1.0f : 0.0f;
            const f32x4 m4 = {mk, mk, mk, mk};
            acc[r] += m4 * v[j];
          }
        }
      }
      // write: quad qd -> node nlb+qd, channels 4*c16..+3 (8-B stores)
      unsigned short* dst = (unsigned short*)(aggS + (nlb + qd) * LDA) + 4 * c16;
#pragma unroll
      for (int r = 0; r < 8; ++r) {
        ushort4 b;
        b.x = f2bf(acc[r][0]); b.y = f2bf(acc[r][1]);
        b.z = f2bf(acc[r][2]); b.w = f2bf(acc[r][3]);
        *(ushort4*)(dst + r * 64) = b;
      }
    } else {
      // generic: full wave per node, lane = channel, wave-uniform switch
#pragma unroll
      for (int t = 0; t < 4; ++t) {
        const int nl = nlb + t;
        float a[8] = {0.f, 0.f, 0.f, 0.f, 0.f, 0.f, 0.f, 0.f};
        if (node0 + nl < num_nodes) {
          const int e0 = ptrS[nl] - e_lo, e1 = ptrS[nl + 1] - e_lo;
          for (int e = e0; e < e1; ++e) {
            unsigned mm;
            if (staged) mm = eMeta[e];
            else {
              const int ge = e_lo + e;
              mm = (unsigned)(idx64 ? i32[2 * ge] : i32[ge]) |
                   ((unsigned)(idx64 ? t32[2 * ge] : t32[ge]) << 24);
            }
            const float vv = (float)xp[(size_t)(mm & 0x00FFFFFFu) * 64 + lane];
            const int r = __builtin_amdgcn_readfirstlane((int)(mm >> 24));
            ACC_SW(a, r, vv)
          }
        }
#pragma unroll
        for (int r = 0; r < 8; ++r)
          aggS[nl * LDA + r * 64 + lane] = __float2bfloat16(a[r]);
      }
    }
  };

  if (x_bf16) {
    const __hip_bfloat16* xb = (const __hip_bfloat16*)xv;
    auto lr = [&](int src, int c) -> f32x4 {
      const ushort4 u = ((const ushort4*)xv)[(size_t)src * 16 + c];
      f32x4 f;
      f[0] = __uint_as_float((unsigned)(unsigned short)u.x << 16);
      f[1] = __uint_as_float((unsigned)(unsigned short)u.y << 16);
      f[2] = __uint_as_float((unsigned)(unsigned short)u.z << 16);
      f[3] = __uint_as_float((unsigned)(unsigned short)u.w << 16);
      return f;
    };
    gather(xb, lr);
  } else {
    const float* xf = (const float*)xv;
    auto lr = [&](int src, int c) -> f32x4 {
      return ((const f32x4*)xv)[(size_t)src * 16 + c];
    };
    gather(xf, lr);
  }

  __syncthreads();

  // ---- MFMA: out_tile[32x64] = agg[32x512] @ Wcat[512x64] ----
  // 8 waves: mt = wvid>>2 (0..1 row-tiles), nt = wvid&3 (0..3 col-tiles)
  const int mt = wvid >> 2;
  const int nt = wvid & 3;
  const int mi = lane & 15;
  const int q4 = lane >> 4;
  const __hip_bfloat16* ap = aggS + (mt * 16 + mi) * LDA + q4 * 8;
  f32x4 c0 = {0.f, 0.f, 0.f, 0.f};
  if (wsB) {
    const bf16x8* B = (const bf16x8*)wsB;
#pragma unroll
    for (int kt = 0; kt < KDIM / 32; ++kt) {
      const bf16x8 a = *(const bf16x8*)(ap + kt * 32);
      const bf16x8 b = B[(nt * 16 + kt) * 64 + lane];
      c0 = __builtin_amdgcn_mfma_f32_16x16x32_bf16(a, b, c0, 0, 0, 0);
    }
  } else {
    const __hip_bfloat16* bp = wtS + (nt * 16 + mi) * LDA + q4 * 8;
#pragma unroll
    for (int kt = 0; kt < KDIM / 32; ++kt) {
      const bf16x8 a = *(const bf16x8*)(ap + kt * 32);
      const bf16x8 b = *(const bf16x8*)(bp + kt * 32);
      c0 = __builtin_amdgcn_mfma_f32_16x16x32_bf16(a, b, c0, 0, 0, 0);
    }
  }

  // D layout: col = lane&15, row = q4*4 + reg -> fp32 stores
#pragma unroll
  for (int i = 0; i < 4; ++i) {
    const int row  = q4 * 4 + i;
    const int nl   = mt * 16 + row;
    const int node = node0 + nl;
    if (node < num_nodes) {
      out[(size_t)node * 64 + nt * 16 + mi] = c0[i] * invS[nl];
    }
  }
}

extern "C" void kernel_launch(void* const* d_in, const int* in_sizes, int n_in,
                              void* d_out, int out_size, void* d_ws, size_t ws_size,
                              hipStream_t stream) {
  const void* x   = d_in[0];
  const void* w   = d_in[1];
  const int*  ptr = (const int*)d_in[2];
  const int*  idx = (const int*)d_in[3];
  const int*  et  = (const int*)d_in[4];
  float*      out = (float*)d_out;

  const int num_nodes = in_sizes[0] / 64;   // x is [N, 64]

  const bool useWs = (d_ws != nullptr) &&
                     (ws_size >= (size_t)WFRAG * sizeof(unsigned short));
  unsigned short* wsB = useWs ? (unsigned short*)d_ws : nullptr;
  if (useWs) pack_w<<<32, 256, 0, stream>>>(w, wsB);

  const size_t lds_bytes = (size_t)NPB * LDA * 2 +
                           (useWs ? 0 : (size_t)64 * LDA * 2) +
                           256 + 144 + (size_t)MAXE * 4;

  hipFuncSetAttribute((const void*)rgcn_fused,
                      hipFuncAttributeMaxDynamicSharedMemorySize,
                      (int)lds_bytes);

  const int nblocks = (num_nodes + NPB - 1) / NPB;
  rgcn_fused<<<nblocks, THREADS, lds_bytes, stream>>>(x, w, ptr, idx, et, wsB,
                                                      out, num_nodes);
}